// Round 9
// baseline (195.652 us; speedup 1.0000x reference)
//
#include <hip/hip_runtime.h>
#include <stdint.h>

// Problem constants
#define NN 4096
#define KSEL 1677721u            // int(4096*4096*0.1)
#define INV_SQRT_DK 0.17677669529663687f  // 1/sqrt(32)

// Workspace layout (bytes)
#define OFF_QH 0u                     // bf16 Q [4096][128] = 1 MB
#define OFF_KH (1u<<20)               // bf16 K 1 MB
#define OFF_STATS (2u<<20)            // 4096 * float2 = 32 KB
#define OFF_H   (3u<<20)              // 256 partial hists x 1024 u32 = 1 MB
#define OFF_H2  (4u<<20)              // 8 partial hists = 32 KB
#define OFF_ST  ((4u<<20) + 65536u)   // state
#define OFF_SB  (16u<<20)             // bf16 scores 32 MB (only if ws >= 48MB)
#define WS_NEED_B16 (48u<<20)

typedef __attribute__((ext_vector_type(8))) short bf16x8;
typedef __attribute__((ext_vector_type(8))) unsigned short u16x8;
typedef __attribute__((ext_vector_type(4))) float f32x4;

static __device__ __forceinline__ short f2bf(float f) {
    unsigned u = __float_as_uint(f);
    unsigned r = (u + 0x7FFFu + ((u >> 16) & 1u)) >> 16;   // RNE
    return (short)r;
}
static __device__ __forceinline__ float bf2f(short h) {
    return __uint_as_float(((unsigned)(unsigned short)h) << 16);
}

// ---------------------------------------------------------------------------
// 1) Projection, one pass, no partials. Grid 1024 = b(4) x 16-row tiles(256).
//    512 thr = 8 waves, F split 8-ways across waves (f-chunk 8).
//    Lane = n_local(16) x colgroup(4): cg0/1 = Q cols 0-15/16-31,
//    cg2/3 = K cols. W slices are VECTOR loads (broadcast within 16-lane
//    group), double-buffered in registers across t -> no SGPR serial stall.
//    One LDS tree-reduce (pad 17) then direct bf16 Qh/Kh stores.
// ---------------------------------------------------------------------------
__global__ __launch_bounds__(512, 4) void proj_kernel(
    const float* __restrict__ x, const float* __restrict__ WQ,
    const float* __restrict__ WK,
    short* __restrict__ Qh, short* __restrict__ Kh)
{
    __shared__ float red[8 * 1089];   // 8 waves x (64 lanes * 17 pad) ~34.8KB
    const int bx  = blockIdx.x;
    const int b   = bx >> 8;
    const int n0  = (bx & 255) << 4;
    const int tid = threadIdx.x;
    const int l   = tid & 63;
    const int w   = __builtin_amdgcn_readfirstlane(tid >> 6); // 0..7
    const int nl  = l & 15;
    const int cg  = l >> 4;                                   // 0..3
    const int n   = n0 + nl;

    const float* __restrict__ Wbase = (cg < 2) ? WQ : WK;
    const int coff = (cg & 1) << 4;

    float acc[16];
#pragma unroll
    for (int j = 0; j < 16; ++j) acc[j] = 0.f;

    const float* xp = x + (size_t)b * 3145728 + (size_t)(w * 8) * 49152 + (size_t)n * 12;

    for (int f = 0; f < 8; ++f) {
        // this lane's 12 x values (redundant across cg; L1 absorbs)
        float4 a0 = *(const float4*)(xp);
        float4 a1 = *(const float4*)(xp + 4);
        float4 a2 = *(const float4*)(xp + 8);
        const float xv[12] = {a0.x, a0.y, a0.z, a0.w,
                              a1.x, a1.y, a1.z, a1.w,
                              a2.x, a2.y, a2.z, a2.w};
        const int fg = w * 8 + f;

        // W double-buffer: load t+1 while FMA-ing t
        const float* wr = Wbase + (size_t)(fg << 5) + coff;   // row (t<<6)+fg
        float4 c0 = *(const float4*)(wr);
        float4 c1 = *(const float4*)(wr + 4);
        float4 c2 = *(const float4*)(wr + 8);
        float4 c3 = *(const float4*)(wr + 12);
#pragma unroll
        for (int t = 0; t < 12; ++t) {
            float4 n0v, n1v, n2v, n3v;
            if (t < 11) {
                const float* wn = Wbase + (size_t)((((t + 1) << 6) + fg) << 5) + coff;
                n0v = *(const float4*)(wn);
                n1v = *(const float4*)(wn + 4);
                n2v = *(const float4*)(wn + 8);
                n3v = *(const float4*)(wn + 12);
            }
            const float xt = xv[t];
            acc[0]  = fmaf(xt, c0.x, acc[0]);  acc[1]  = fmaf(xt, c0.y, acc[1]);
            acc[2]  = fmaf(xt, c0.z, acc[2]);  acc[3]  = fmaf(xt, c0.w, acc[3]);
            acc[4]  = fmaf(xt, c1.x, acc[4]);  acc[5]  = fmaf(xt, c1.y, acc[5]);
            acc[6]  = fmaf(xt, c1.z, acc[6]);  acc[7]  = fmaf(xt, c1.w, acc[7]);
            acc[8]  = fmaf(xt, c2.x, acc[8]);  acc[9]  = fmaf(xt, c2.y, acc[9]);
            acc[10] = fmaf(xt, c2.z, acc[10]); acc[11] = fmaf(xt, c2.w, acc[11]);
            acc[12] = fmaf(xt, c3.x, acc[12]); acc[13] = fmaf(xt, c3.y, acc[13]);
            acc[14] = fmaf(xt, c3.z, acc[14]); acc[15] = fmaf(xt, c3.w, acc[15]);
            if (t < 11) { c0 = n0v; c1 = n1v; c2 = n2v; c3 = n3v; }
        }
        xp += 49152;
    }

    // stage per-wave partials
    float* rp = &red[w * 1089 + l * 17];
#pragma unroll
    for (int j = 0; j < 16; ++j) rp[j] = acc[j];
    __syncthreads();

    // 1024 outputs (64 ln x 16 j), 512 threads -> 2 each; sum 8 waves
#pragma unroll
    for (int h = 0; h < 2; ++h) {
        const int o  = tid + h * 512;
        const int ln = o >> 4, j = o & 15;
        float s = 0.f;
#pragma unroll
        for (int w2 = 0; w2 < 8; ++w2) s += red[w2 * 1089 + ln * 17 + j];
        const int nl2 = ln & 15, cg2 = ln >> 4;
        const size_t idx = (size_t)(n0 + nl2) * 128 + (b << 5) + ((cg2 & 1) << 4) + j;
        if (cg2 < 2) Qh[idx] = f2bf(s * INV_SQRT_DK);
        else         Kh[idx] = f2bf(s);
    }
}

// ---------------------------------------------------------------------------
// 2) S = Q @ K^T via MFMA 16x16x32 bf16. 128x128 tile per 256-thread block,
//    wave tile 64x64 (4x4 frags), 2-deep register ping-pong prefetch.
// ---------------------------------------------------------------------------
template<bool B16>
__global__ __launch_bounds__(256, 3) void gemm_kernel(
    const short* __restrict__ Qh, const short* __restrict__ Kh, void* Sv)
{
    const int bi = blockIdx.x >> 5, bj = blockIdx.x & 31;
    const int tid = threadIdx.x;
    const int w = tid >> 6, l = tid & 63;
    const int m0 = bi * 128 + (w >> 1) * 64;
    const int n0 = bj * 128 + (w & 1) * 64;
    const int lr = l & 15;
    const int kg = (l >> 4) * 8;

    f32x4 acc[4][4];
#pragma unroll
    for (int i = 0; i < 4; ++i)
#pragma unroll
        for (int j = 0; j < 4; ++j) acc[i][j] = (f32x4){0.f, 0.f, 0.f, 0.f};

    bf16x8 aA[4], bA[4], aB[4], bB[4];

    auto LD = [&](bf16x8* A, bf16x8* B, int k0) {
#pragma unroll
        for (int i = 0; i < 4; ++i) {
            A[i] = *(const bf16x8*)(Qh + (size_t)(m0 + i * 16 + lr) * 128 + k0 + kg);
            B[i] = *(const bf16x8*)(Kh + (size_t)(n0 + i * 16 + lr) * 128 + k0 + kg);
        }
    };
    auto DOMFMA = [&](bf16x8* A, bf16x8* B) {
#pragma unroll
        for (int i = 0; i < 4; ++i)
#pragma unroll
            for (int j = 0; j < 4; ++j)
                acc[i][j] = __builtin_amdgcn_mfma_f32_16x16x32_bf16(A[i], B[j], acc[i][j], 0, 0, 0);
    };

    LD(aA, bA, 0);
    LD(aB, bB, 32);
    DOMFMA(aA, bA);  LD(aA, bA, 64);
    DOMFMA(aB, bB);  LD(aB, bB, 96);
    DOMFMA(aA, bA);
    DOMFMA(aB, bB);

    // C/D mapping (m89-verified): col = lane&15, row = (lane>>4)*4 + reg
#pragma unroll
    for (int i = 0; i < 4; ++i) {
        int rowb = m0 + i * 16 + (l >> 4) * 4;
#pragma unroll
        for (int j = 0; j < 4; ++j) {
            int col = n0 + j * 16 + (l & 15);
#pragma unroll
            for (int r = 0; r < 4; ++r) {
                if constexpr (B16)
                    ((unsigned short*)Sv)[(size_t)(rowb + r) * NN + col] =
                        (unsigned short)f2bf(acc[i][j][r]);
                else
                    ((float*)Sv)[(size_t)(rowb + r) * NN + col] = acc[i][j][r];
            }
        }
    }
}

// ---------------------------------------------------------------------------
// 3) Fused row stats + histogram. One wave per row, row in registers.
//    Each block OWNS partial-hist slot blockIdx.x (full overwrite, no memset).
// ---------------------------------------------------------------------------
template<bool B16>
__global__ __launch_bounds__(512) void histstat_kernel(
    const void* __restrict__ Sv, float2* __restrict__ stats,
    unsigned* __restrict__ gh)
{
    __shared__ unsigned h[1024];
    const int tid = threadIdx.x;
    const int l = tid & 63;
    const int w = tid >> 6;

    for (int i = tid; i < 1024; i += 512) h[i] = 0;
    __syncthreads();

#pragma unroll
    for (int r = 0; r < 2; ++r) {
        const int row = (blockIdx.x << 4) + (r << 3) + w;

        float v[64];
        if constexpr (B16) {
            const u16x8* rp = (const u16x8*)((const unsigned short*)Sv + (size_t)row * NN);
#pragma unroll
            for (int j = 0; j < 8; ++j) {
                u16x8 e = rp[l + (j << 6)];
#pragma unroll
                for (int i = 0; i < 8; ++i) v[j * 8 + i] = bf2f((short)e[i]);
            }
        } else {
            const float4* rp = (const float4*)((const float*)Sv + (size_t)row * NN);
#pragma unroll
            for (int j = 0; j < 16; ++j) {
                float4 t = rp[l + (j << 6)];
                v[j * 4 + 0] = t.x; v[j * 4 + 1] = t.y;
                v[j * 4 + 2] = t.z; v[j * 4 + 3] = t.w;
            }
        }

        float m = -3.4e38f;
#pragma unroll
        for (int j = 0; j < 64; ++j) m = fmaxf(m, v[j]);
#pragma unroll
        for (int off = 32; off; off >>= 1) m = fmaxf(m, __shfl_xor(m, off));

        float s = 0.f;
#pragma unroll
        for (int j = 0; j < 64; ++j) { v[j] = __expf(v[j] - m); s += v[j]; }
#pragma unroll
        for (int off = 32; off; off >>= 1) s += __shfl_xor(s, off);
        const float inv = 1.0f / s;
        if (l == 0) stats[row] = make_float2(m, inv);

#pragma unroll
        for (int j = 0; j < 64; ++j) {
            int b0 = min(max((int)(__float_as_uint(v[j] * inv) >> 16) - 0x3780, 0), 1023);
            atomicAdd(&h[b0], 1u);
        }
    }

    __syncthreads();
    unsigned* dst = gh + ((unsigned)blockIdx.x << 10);
    for (int i = tid; i < 1024; i += 512) dst[i] = h[i];   // full overwrite
}

// ---------------------------------------------------------------------------
// 4a) Pre-reduce 256 partials -> 8.   4b) Final reduce + suffix-scan.
// ---------------------------------------------------------------------------
__global__ __launch_bounds__(1024) void reduce_kernel(
    const unsigned* __restrict__ gh, unsigned* __restrict__ gh2)
{
    const int t = threadIdx.x, b = blockIdx.x;
    unsigned s = 0;
    for (int p = 0; p < 32; ++p) s += gh[((unsigned)(b * 32 + p) << 10) + t];
    gh2[((unsigned)b << 10) + t] = s;
}

__global__ __launch_bounds__(1024) void scan_kernel(
    const unsigned* __restrict__ gh2, unsigned* st)
{
    __shared__ unsigned P[1024];
    const int t = threadIdx.x;
    unsigned s = 0;
#pragma unroll
    for (int p = 0; p < 8; ++p) s += gh2[(p << 10) + t];
    P[t] = s;
    __syncthreads();
    for (int off = 1; off < 1024; off <<= 1) {
        unsigned v = P[t] + ((t + off < 1024) ? P[t + off] : 0u);
        __syncthreads();
        P[t] = v;
        __syncthreads();
    }
    if (P[t] >= KSEL && (t == 1023 || P[t + 1] < KSEL))
        st[2] = (0x3780u + (unsigned)t) << 16;   // lower edge of selected bin
}

// ---------------------------------------------------------------------------
// 5) Final: recompute p, threshold -> keep; else dropout (x1/0.9 or 0).
// ---------------------------------------------------------------------------
template<bool B16>
__global__ __launch_bounds__(256) void final_kernel(
    const void* __restrict__ Sv, float* __restrict__ out,
    const float4* __restrict__ u4,
    const float2* __restrict__ stats, const unsigned* __restrict__ st)
{
    const int row = blockIdx.x;
    const float thr = __uint_as_float(st[2]);
    const float2 stt = stats[row];
    float4* o4 = (float4*)(out + (size_t)row * NN);
    const float4* u = u4 + (size_t)row * 1024;
    for (int i = threadIdx.x; i < 1024; i += 256) {
        float4 v;
        if constexpr (B16) {
            ushort4 s4 = ((const ushort4*)((const unsigned short*)Sv + (size_t)row * NN))[i];
            v.x = bf2f((short)s4.x); v.y = bf2f((short)s4.y);
            v.z = bf2f((short)s4.z); v.w = bf2f((short)s4.w);
        } else {
            v = ((const float4*)((const float*)Sv + (size_t)row * NN))[i];
        }
        float4 uu = u[i];
        float4 o;
        float p;
        p = __expf(v.x - stt.x) * stt.y;
        o.x = (p >= thr) ? p : ((uu.x >= 0.1f) ? p * (1.0f / 0.9f) : 0.0f);
        p = __expf(v.y - stt.x) * stt.y;
        o.y = (p >= thr) ? p : ((uu.y >= 0.1f) ? p * (1.0f / 0.9f) : 0.0f);
        p = __expf(v.z - stt.x) * stt.y;
        o.z = (p >= thr) ? p : ((uu.z >= 0.1f) ? p * (1.0f / 0.9f) : 0.0f);
        p = __expf(v.w - stt.x) * stt.y;
        o.w = (p >= thr) ? p : ((uu.w >= 0.1f) ? p * (1.0f / 0.9f) : 0.0f);
        o4[i] = o;
    }
}

extern "C" void kernel_launch(void* const* d_in, const int* in_sizes, int n_in,
                              void* d_out, int out_size, void* d_ws, size_t ws_size,
                              hipStream_t stream)
{
    const float* x  = (const float*)d_in[0];
    const float* WQ = (const float*)d_in[1];
    const float* WK = (const float*)d_in[2];
    const float* du = (const float*)d_in[3];
    float* out = (float*)d_out;
    char* ws = (char*)d_ws;

    short* Qh = (short*)(ws + OFF_QH);
    short* Kh = (short*)(ws + OFF_KH);
    float2* stats = (float2*)(ws + OFF_STATS);
    unsigned* hist = (unsigned*)(ws + OFF_H);
    unsigned* gh2  = (unsigned*)(ws + OFF_H2);
    unsigned* st   = (unsigned*)(ws + OFF_ST);

    proj_kernel<<<1024, 512, 0, stream>>>(x, WQ, WK, Qh, Kh);

    const bool b16 = (ws_size >= (size_t)WS_NEED_B16);   // fixed per process -> graph-safe
    if (b16) {
        void* Sb = (void*)(ws + OFF_SB);
        gemm_kernel<true><<<1024, 256, 0, stream>>>(Qh, Kh, Sb);
        histstat_kernel<true><<<256, 512, 0, stream>>>(Sb, stats, hist);
        reduce_kernel<<<8, 1024, 0, stream>>>(hist, gh2);
        scan_kernel<<<1, 1024, 0, stream>>>(gh2, st);
        final_kernel<true><<<NN, 256, 0, stream>>>(Sb, out, (const float4*)du, stats, st);
    } else {
        gemm_kernel<false><<<1024, 256, 0, stream>>>(Qh, Kh, (void*)out);
        histstat_kernel<false><<<256, 512, 0, stream>>>((void*)out, stats, hist);
        reduce_kernel<<<8, 1024, 0, stream>>>(hist, gh2);
        scan_kernel<<<1, 1024, 0, stream>>>(gh2, st);
        final_kernel<false><<<NN, 256, 0, stream>>>((void*)out, out, (const float4*)du, stats, st);
    }
}